// Round 5
// baseline (291.633 us; speedup 1.0000x reference)
//
#include <hip/hip_runtime.h>
#include <math.h>

#define DIM 768
#define HEADS 4
#define HDIM 3072   // HEADS*DIM
#define BATCH 128

// ---------------------------------------------------------------------------
// R4 history: bf16 MFMA GEMM passed (absmax 0.016) but 47us/stage at 2% Mfma,
// 12% HBM, 15% occ -- latency-bound: __syncthreads drained vmcnt(0) every
// K-step, exposing ~600cyc of HBM latency 12x per block at 1.8 blocks/CU.
// R5: (1) raw s_barrier + lgkmcnt(0) only (loads stay in flight, T4),
// (2) depth-2 register prefetch with fully static sets (rule #20),
// (3) BN=64 tiles -> 2x grid, 12KB LDS, ~64 VGPR -> 4 waves/SIMD overlap.
// All 27 sub-GEMMs have K=768 -> nk=24 hardcoded, loop unrolled x2.
// ---------------------------------------------------------------------------
typedef __attribute__((ext_vector_type(8))) short bfrag;   // 8 bf16 = 4 VGPR
typedef __attribute__((ext_vector_type(4))) float f32x4;

struct GemmDesc {
    const float* A;   // M x K, row stride lda
    const float* B;   // N x K, row stride ldb
    const float* bias;
    float* C;         // M x N, row stride ldc
    int lda, ldb, ldc;
    int M, N, K;
    int blockBase;    // first 1-D block id of this sub-problem
    int nTiles;       // N/64
};
#define MAXD 12
struct GemmBatch { GemmDesc d[MAXD]; int nDesc; };

__device__ inline short f2bf(float f) {   // RTNE fp32 -> bf16
    unsigned u = __float_as_uint(f);
    u += 0x7FFF + ((u >> 16) & 1);
    return (short)(u >> 16);
}

// lgkmcnt(0) for LDS writes, raw barrier (does NOT drain vmcnt -> global
// prefetch loads stay in flight), sched fence against ds_read hoisting.
#define BAR() do { \
    asm volatile("s_waitcnt lgkmcnt(0)" ::: "memory"); \
    __builtin_amdgcn_s_barrier(); \
    __builtin_amdgcn_sched_barrier(0); \
} while (0)

__global__ __launch_bounds__(256) void gemm_bf16(GemmBatch batch)
{
    // fragment-ordered bf16 tiles, BK=32: A 32x32 (2 regions), B 64x32 (4).
    // slot S (8B=short4): region=S>>7, lane=(S&127)>>1, j2=S&1;
    // row = region*16 + (lane&15), k = (lane>>4)*8 + j2*4.
    __shared__ __attribute__((aligned(16))) short Asl[2][1024];
    __shared__ __attribute__((aligned(16))) short Bsl[2][2048];

    int bid = blockIdx.x;
    int di = 0;
    while (di + 1 < batch.nDesc && bid >= batch.d[di + 1].blockBase) ++di;
    const GemmDesc g = batch.d[di];
    int lb = bid - g.blockBase;
    int mt = lb / g.nTiles;
    int nt = lb - mt * g.nTiles;
    const int m0 = mt * 32, n0 = nt * 64;
    const int M = g.M, lda = g.lda, ldb = g.ldb;
    const float* __restrict__ A = g.A;
    const float* __restrict__ B = g.B;

    const int tid = threadIdx.x;
    const int lane = tid & 63;
    const int w = tid >> 6;          // wave id = 16-col n-strip

    // ---- staging offsets: A slot = tid; B slots = tid, tid+256 ----
    int aoff; bool aok;
    {
        int rg = tid >> 7, h = tid & 127, l = h >> 1, j2 = h & 1;
        int m = rg * 16 + (l & 15);
        int k = (l >> 4) * 8 + j2 * 4;
        aok = (m0 + m) < M;
        aoff = (m0 + m) * lda + k;
    }
    int boff0, boff1;
    {
        int h = tid & 127, l = h >> 1, j2 = h & 1;
        int k = (l >> 4) * 8 + j2 * 4;
        int ng0 = tid >> 7;          // 0,1
        boff0 = (n0 + ng0 * 16 + (l & 15)) * ldb + k;
        boff1 = (n0 + (ng0 + 2) * 16 + (l & 15)) * ldb + k;
    }

    const float4 fz = { 0.f, 0.f, 0.f, 0.f };
    float4 pa0, pb00, pb01, pa1, pb10, pb11;   // two named prefetch sets

#define LOAD0(t) do { int k0 = (t) * 32; \
    pa0  = aok ? *(const float4*)(A + aoff + k0) : fz; \
    pb00 = *(const float4*)(B + boff0 + k0); \
    pb01 = *(const float4*)(B + boff1 + k0); } while (0)
#define LOAD1(t) do { int k0 = (t) * 32; \
    pa1  = aok ? *(const float4*)(A + aoff + k0) : fz; \
    pb10 = *(const float4*)(B + boff0 + k0); \
    pb11 = *(const float4*)(B + boff1 + k0); } while (0)
#define CVT(dst, v) do { short4 s_; \
    s_.x = f2bf((v).x); s_.y = f2bf((v).y); s_.z = f2bf((v).z); s_.w = f2bf((v).w); \
    *(short4*)(dst) = s_; } while (0)
#define WRITE0(bf) do { \
    CVT(&Asl[bf][tid * 4], pa0); \
    CVT(&Bsl[bf][tid * 4], pb00); \
    CVT(&Bsl[bf][(tid + 256) * 4], pb01); } while (0)
#define WRITE1(bf) do { \
    CVT(&Asl[bf][tid * 4], pa1); \
    CVT(&Bsl[bf][tid * 4], pb10); \
    CVT(&Bsl[bf][(tid + 256) * 4], pb11); } while (0)

    f32x4 acc0 = {0.f, 0.f, 0.f, 0.f};
    f32x4 acc1 = {0.f, 0.f, 0.f, 0.f};

#define COMPUTE(bf) do { \
    bfrag a0 = *(const bfrag*)&Asl[bf][lane * 8]; \
    bfrag a1 = *(const bfrag*)&Asl[bf][512 + lane * 8]; \
    bfrag bb = *(const bfrag*)&Bsl[bf][w * 512 + lane * 8]; \
    acc0 = __builtin_amdgcn_mfma_f32_16x16x32_bf16(a0, bb, acc0, 0, 0, 0); \
    acc1 = __builtin_amdgcn_mfma_f32_16x16x32_bf16(a1, bb, acc1, 0, 0, 0); \
} while (0)

    // ---- software pipeline: depth-2 prefetch, even tiles buf0, odd buf1 ----
    LOAD0(0); LOAD1(1);
    WRITE0(0);                 // compiler: counted vmcnt (set1 stays in flight)
    BAR();
#pragma unroll 1
    for (int t = 0; t < 22; t += 2) {
        LOAD0(t + 2);          // in flight across 2 barriers
        COMPUTE(0);            // tile t
        WRITE1(1);             // tile t+1 (loaded one iteration ago)
        BAR();
        LOAD1(t + 3);
        COMPUTE(1);            // tile t+1
        WRITE0(0);             // tile t+2
        BAR();
    }
    COMPUTE(0);                // tile 22
    WRITE1(1);
    BAR();
    COMPUTE(1);                // tile 23

    // ---- epilogue: D layout col=lane&15, row=(lane>>4)*4+r (m89-verified) ----
    const int gq = lane >> 4;
    const int cn = lane & 15;
    const int n = n0 + w * 16 + cn;
    float bv = g.bias ? g.bias[n] : 0.f;
#pragma unroll
    for (int r = 0; r < 4; ++r) {
        int m = m0 + gq * 4 + r;
        if (m < M) g.C[(long)m * g.ldc + n] = acc0[r] + bv;
    }
#pragma unroll
    for (int r = 0; r < 4; ++r) {
        int m = m0 + 16 + gq * 4 + r;
        if (m < M) g.C[(long)m * g.ldc + n] = acc1[r] + bv;
    }
#undef LOAD0
#undef LOAD1
#undef CVT
#undef WRITE0
#undef WRITE1
#undef COMPUTE
}

// ---------------------------------------------------------------------------
// Fused attention row-0 + FC + 2x LN + score (unchanged -- profile next).
// ---------------------------------------------------------------------------
struct ScoreDesc {
    const float *tok_q, *tok_k, *k_task, *U_tok, *U_task, *tokens;
    const float *fcb, *lng, *lnb, *slng, *slnb, *sw, *sbias;
    int T, outOff, blockBase, pad;
};
struct ScoreBatch { ScoreDesc d[2]; };

__device__ inline void block_reduce2(float& a, float& b, float* redA, float* redB, int tid)
{
    int lane = tid & 63, wave = tid >> 6;
#pragma unroll
    for (int off = 32; off; off >>= 1) {
        a += __shfl_down(a, off);
        b += __shfl_down(b, off);
    }
    if (lane == 0) { redA[wave] = a; redB[wave] = b; }
    __syncthreads();
    a = redA[0] + redA[1] + redA[2] + redA[3];
    b = redB[0] + redB[1] + redB[2] + redB[3];
    __syncthreads();
}

__global__ __launch_bounds__(256) void score_kernel(ScoreBatch batch, float* __restrict__ out)
{
    const int si = (blockIdx.x >= batch.d[1].blockBase) ? 1 : 0;
    const ScoreDesc g = batch.d[si];
    const int bid = blockIdx.x - g.blockBase;
    const int T = g.T;
    const int b = bid / T;
    const int t = bid - b * T;
    const int tid = threadIdx.x;
    const int lane = tid & 63;
    const int wave = tid >> 6;   // == head

    __shared__ float coef[HEADS][2];
    __shared__ float redA[4], redB[4];

    {
        const float4* q4  = (const float4*)(g.tok_q  + (long)t * HDIM + wave * DIM);
        const float4* kt4 = (const float4*)(g.tok_k  + (long)t * HDIM + wave * DIM);
        const float4* kb4 = (const float4*)(g.k_task + (long)b * HDIM + wave * DIM);
        float s00 = 0.f, s01 = 0.f;
#pragma unroll
        for (int j = 0; j < 3; ++j) {
            int idx = lane + 64 * j;
            float4 qv = q4[idx], kt = kt4[idx], kb = kb4[idx];
            s00 += qv.x * kt.x + qv.y * kt.y + qv.z * kt.z + qv.w * kt.w;
            s01 += qv.x * kb.x + qv.y * kb.y + qv.z * kb.z + qv.w * kb.w;
        }
#pragma unroll
        for (int off = 32; off; off >>= 1) {
            s00 += __shfl_down(s00, off);
            s01 += __shfl_down(s01, off);
        }
        if (lane == 0) {
            const float scale = 0.03608439182435161f;  // 1/sqrt(768)
            float x0 = s00 * scale, x1 = s01 * scale;
            float mx = fmaxf(x0, x1);
            float e0 = expf(x0 - mx), e1 = expf(x1 - mx);
            float inv = 1.f / (e0 + e1);
            coef[wave][0] = e0 * inv;
            coef[wave][1] = e1 * inv;
        }
    }
    __syncthreads();

    const float c00 = coef[0][0], c01 = coef[0][1];
    const float c10 = coef[1][0], c11 = coef[1][1];
    const float c20 = coef[2][0], c21 = coef[2][1];
    const float c30 = coef[3][0], c31 = coef[3][1];

    float r[3];
    float sum = 0.f, sq = 0.f;
    const float* Ut = g.U_tok  + (long)t * HDIM;
    const float* Ub = g.U_task + (long)b * HDIM;
#pragma unroll
    for (int j = 0; j < 3; ++j) {
        int d = tid + j * 256;
        float v = g.fcb[d] + g.tokens[(long)t * DIM + d];
        v += c00 * Ut[d]           + c01 * Ub[d];
        v += c10 * Ut[DIM + d]     + c11 * Ub[DIM + d];
        v += c20 * Ut[2 * DIM + d] + c21 * Ub[2 * DIM + d];
        v += c30 * Ut[3 * DIM + d] + c31 * Ub[3 * DIM + d];
        r[j] = v;
        sum += v;
        sq += v * v;
    }
    block_reduce2(sum, sq, redA, redB, tid);
    float mean = sum * (1.f / DIM);
    float var = sq * (1.f / DIM) - mean * mean;
    float inv = rsqrtf(var + 1e-5f);

    float y[3];
    float sum2 = 0.f, sq2 = 0.f;
#pragma unroll
    for (int j = 0; j < 3; ++j) {
        int d = tid + j * 256;
        float v = (r[j] - mean) * inv * g.lng[d] + g.lnb[d];
        y[j] = v;
        sum2 += v;
        sq2 += v * v;
    }
    block_reduce2(sum2, sq2, redA, redB, tid);
    float mean2 = sum2 * (1.f / DIM);
    float var2 = sq2 * (1.f / DIM) - mean2 * mean2;
    float inv2 = rsqrtf(var2 + 1e-5f);

    float partial = 0.f, dummy = 0.f;
#pragma unroll
    for (int j = 0; j < 3; ++j) {
        int d = tid + j * 256;
        float c = (y[j] - mean2) * inv2 * g.slng[d] + g.slnb[d];
        partial += c * g.sw[d];
    }
    block_reduce2(partial, dummy, redA, redB, tid);
    if (tid == 0) out[(long)b * 80 + g.outOff + t] = partial + g.sbias[0];
}

// ---------------------------------------------------------------------------
extern "C" void kernel_launch(void* const* d_in, const int* in_sizes, int n_in,
                              void* d_out, int out_size, void* d_ws, size_t ws_size,
                              hipStream_t stream)
{
    const float* task_emb    = (const float*)d_in[0];
    const float* tokens_l1   = (const float*)d_in[1];
    const float* tokens_l2   = (const float*)d_in[2];
    const float* task_proj_w = (const float*)d_in[3];
    const float* task_proj_b = (const float*)d_in[4];

    const float* wq1  = (const float*)d_in[5];
    const float* wk1  = (const float*)d_in[6];
    const float* wv1  = (const float*)d_in[7];
    const float* fcw1 = (const float*)d_in[8];
    const float* fcb1 = (const float*)d_in[9];
    const float* lng1 = (const float*)d_in[10];
    const float* lnb1 = (const float*)d_in[11];
    const float* slng1= (const float*)d_in[12];
    const float* slnb1= (const float*)d_in[13];
    const float* sw1  = (const float*)d_in[14];
    const float* sb1  = (const float*)d_in[15];

    const float* wq2  = (const float*)d_in[16];
    const float* wk2  = (const float*)d_in[17];
    const float* wv2  = (const float*)d_in[18];
    const float* fcw2 = (const float*)d_in[19];
    const float* fcb2 = (const float*)d_in[20];
    const float* lng2 = (const float*)d_in[21];
    const float* lnb2 = (const float*)d_in[22];
    const float* slng2= (const float*)d_in[23];
    const float* slnb2= (const float*)d_in[24];
    const float* sw2  = (const float*)d_in[25];
    const float* sb2  = (const float*)d_in[26];

    float* out = (float*)d_out;

    float* ws = (float*)d_ws;
    float* task_p   = ws;
    float* tq1      = task_p   +  98304;
    float* tk1      = tq1      +  49152;
    float* tv1      = tk1      +  49152;
    float* ut1      = tv1      +  49152;
    float* tq2      = ut1      +  49152;
    float* tk2      = tq2      + 196608;
    float* tv2      = tk2      + 196608;
    float* ut2      = tv2      + 196608;
    float* ktask1   = ut2      + 196608;
    float* vtask1   = ktask1   + 393216;
    float* utask1   = vtask1   + 393216;
    float* ktask2   = utask1   + 393216;
    float* vtask2   = ktask2   + 393216;
    float* utask2   = vtask2   + 393216;

    auto mkDesc = [](const float* A, int lda, const float* B, int ldb,
                     const float* bias, float* C, int ldc,
                     int M, int N, int K, int base) {
        GemmDesc g;
        g.A = A; g.B = B; g.bias = bias; g.C = C;
        g.lda = lda; g.ldb = ldb; g.ldc = ldc;
        g.M = M; g.N = N; g.K = K;
        g.blockBase = base; g.nTiles = N / 64;
        return g;
    };
    auto blocksOf = [](int M, int N) { return ((M + 31) / 32) * (N / 64); };

    // ---- stage A: task_p + token q/k/v projections (7 descs, 480 blocks) ----
    {
        GemmBatch ba; int base = 0, nd = 0;
        ba.d[nd++] = mkDesc(task_emb, DIM, task_proj_w, DIM, task_proj_b,
                            task_p, DIM, BATCH, DIM, DIM, base);
        base += blocksOf(BATCH, DIM);
        const float* tA[2] = { tokens_l1, tokens_l2 };
        int tT[2] = { 16, 64 };
        const float* tW[2][3] = { { wq1, wk1, wv1 }, { wq2, wk2, wv2 } };
        float* tC[2][3] = { { tq1, tk1, tv1 }, { tq2, tk2, tv2 } };
        for (int l = 0; l < 2; ++l)
            for (int w = 0; w < 3; ++w) {
                ba.d[nd++] = mkDesc(tA[l], DIM, tW[l][w], DIM, nullptr,
                                    tC[l][w], HDIM, tT[l], HDIM, DIM, base);
                base += blocksOf(tT[l], HDIM);
            }
        ba.nDesc = nd;
        gemm_bf16<<<dim3(base), dim3(256), 0, stream>>>(ba);
    }

    // ---- stage B: k_task/v_task + U_tok per head (12 descs, 912 blocks) ----
    {
        GemmBatch bb; int base = 0, nd = 0;
        const float* kw[2] = { wk1, wk2 };
        const float* vw[2] = { wv1, wv2 };
        float* kc[2] = { ktask1, ktask2 };
        float* vc[2] = { vtask1, vtask2 };
        for (int l = 0; l < 2; ++l) {
            bb.d[nd++] = mkDesc(task_p, DIM, kw[l], DIM, nullptr,
                                kc[l], HDIM, BATCH, HDIM, DIM, base);
            base += blocksOf(BATCH, HDIM);
            bb.d[nd++] = mkDesc(task_p, DIM, vw[l], DIM, nullptr,
                                vc[l], HDIM, BATCH, HDIM, DIM, base);
            base += blocksOf(BATCH, HDIM);
        }
        const float* fw[2] = { fcw1, fcw2 };
        float* tv[2] = { tv1, tv2 };
        float* ut[2] = { ut1, ut2 };
        int tT[2] = { 16, 64 };
        for (int l = 0; l < 2; ++l)
            for (int h = 0; h < HEADS; ++h) {
                bb.d[nd++] = mkDesc(tv[l] + h * DIM, HDIM, fw[l] + h * DIM, HDIM,
                                    nullptr, ut[l] + h * DIM, HDIM,
                                    tT[l], DIM, DIM, base);
                base += blocksOf(tT[l], DIM);
            }
        bb.nDesc = nd;
        gemm_bf16<<<dim3(base), dim3(256), 0, stream>>>(bb);
    }

    // ---- stage C: U_task per head per level (8 descs, 384 blocks) ----
    {
        GemmBatch bc; int base = 0, nd = 0;
        const float* fw[2] = { fcw1, fcw2 };
        float* vt[2] = { vtask1, vtask2 };
        float* utk[2] = { utask1, utask2 };
        for (int l = 0; l < 2; ++l)
            for (int h = 0; h < HEADS; ++h) {
                bc.d[nd++] = mkDesc(vt[l] + h * DIM, HDIM, fw[l] + h * DIM, HDIM,
                                    nullptr, utk[l] + h * DIM, HDIM,
                                    BATCH, DIM, DIM, base);
                base += blocksOf(BATCH, DIM);
            }
        bc.nDesc = nd;
        gemm_bf16<<<dim3(base), dim3(256), 0, stream>>>(bc);
    }

    // ---- stage D: both score levels, one dispatch ----
    {
        ScoreBatch sb;
        sb.d[0].tok_q = tq1; sb.d[0].tok_k = tk1; sb.d[0].k_task = ktask1;
        sb.d[0].U_tok = ut1; sb.d[0].U_task = utask1; sb.d[0].tokens = tokens_l1;
        sb.d[0].fcb = fcb1; sb.d[0].lng = lng1; sb.d[0].lnb = lnb1;
        sb.d[0].slng = slng1; sb.d[0].slnb = slnb1; sb.d[0].sw = sw1; sb.d[0].sbias = sb1;
        sb.d[0].T = 16; sb.d[0].outOff = 0; sb.d[0].blockBase = 0; sb.d[0].pad = 0;
        sb.d[1].tok_q = tq2; sb.d[1].tok_k = tk2; sb.d[1].k_task = ktask2;
        sb.d[1].U_tok = ut2; sb.d[1].U_task = utask2; sb.d[1].tokens = tokens_l2;
        sb.d[1].fcb = fcb2; sb.d[1].lng = lng2; sb.d[1].lnb = lnb2;
        sb.d[1].slng = slng2; sb.d[1].slnb = slnb2; sb.d[1].sw = sw2; sb.d[1].sbias = sb2;
        sb.d[1].T = 64; sb.d[1].outOff = 16; sb.d[1].blockBase = BATCH * 16; sb.d[1].pad = 0;
        score_kernel<<<dim3(BATCH * 16 + BATCH * 64), dim3(256), 0, stream>>>(sb, out);
    }
}

// Round 7
// 285.214 us; speedup vs baseline: 1.0225x; 1.0225x over previous
//
#include <hip/hip_runtime.h>
#include <hip/hip_bf16.h>
#include <math.h>

#define DIM 768
#define HEADS 4
#define HDIM 3072   // HEADS*DIM
#define BATCH 128

// ---------------------------------------------------------------------------
// R5 history: BK=32 LDS-staged MFMA GEMM was latency-bound at every variant
// (2-47-63us, MfmaUtil ~2%): ~40cyc of MFMA per barrier can't amortize a
// memory round trip. R6: BARRIER-FREE design. Block = 16-row A-panel (full
// K=768, bf16, 24KB LDS, staged once = one barrier total) x 256 cols.
// B streams global->reg->MFMA (weights are L2-resident, shared by blocks);
// 4 indep acc chains/wave; K fully unrolled, depth-2 named prefetch sets.
// (R6 bench was lost to GPUAcquisitionTimeout -- resubmitted unchanged.)
// ---------------------------------------------------------------------------
typedef __attribute__((ext_vector_type(8))) short bfrag;   // 8 bf16 = 4 VGPR
typedef __attribute__((ext_vector_type(4))) float f32x4;

struct GemmDesc {
    const float* A;   // M x 768, row stride lda
    const float* B;   // N x 768, row stride ldb
    const float* bias;
    float* C;         // M x N, row stride ldc
    int lda, ldb, ldc;
    int M, N, K;      // K == 768 always
    int blockBase;    // first 1-D block id of this sub-problem
    int nTiles;       // N/256
};
#define MAXD 12
struct GemmBatch { GemmDesc d[MAXD]; int nDesc; };

__device__ inline short f2bf(float f) {   // HW RTNE convert
    union { __hip_bfloat16 h; short s; } u;
    u.h = __float2bfloat16(f);
    return u.s;
}

__global__ __launch_bounds__(256, 4) void gemm_bf16(GemmBatch batch)
{
    // A panel, fragment-ordered: granule g=(ks,l) holds A[m0+(l&15)][ks*32+(l>>4)*8+0..7]
    __shared__ __attribute__((aligned(16))) short Asl[24 * 512];   // 24 KB

    int bid = blockIdx.x;
    int di = 0;
    while (di + 1 < batch.nDesc && bid >= batch.d[di + 1].blockBase) ++di;
    const GemmDesc g = batch.d[di];
    int lb = bid - g.blockBase;
    int mt = lb / g.nTiles;
    int nt = lb - mt * g.nTiles;
    const int m0 = mt * 16, n0 = nt * 256;
    const int lda = g.lda, ldb = g.ldb;
    const float* __restrict__ A = g.A;
    const float* __restrict__ B = g.B;

    const int tid = threadIdx.x;
    const int lane = tid & 63;
    const int w = tid >> 6;

    // ---- stage A panel: 16 rows x 768 k -> bf16 LDS (once; one barrier) ----
#pragma unroll
    for (int i = 0; i < 6; ++i) {
        int gI = tid + 256 * i;              // granule id: ks = gI>>6, l = gI&63
        int ks = gI >> 6, l = gI & 63;
        const float* src = A + (long)(m0 + (l & 15)) * lda + ks * 32 + ((l >> 4) << 3);
        float4 v0 = *(const float4*)src;
        float4 v1 = *(const float4*)(src + 4);
        short4 s0, s1;
        s0.x = f2bf(v0.x); s0.y = f2bf(v0.y); s0.z = f2bf(v0.z); s0.w = f2bf(v0.w);
        s1.x = f2bf(v1.x); s1.y = f2bf(v1.y); s1.z = f2bf(v1.z); s1.w = f2bf(v1.w);
        *(short4*)&Asl[gI * 8]     = s0;
        *(short4*)&Asl[gI * 8 + 4] = s1;
    }
    __syncthreads();   // the ONLY barrier

    // ---- B streaming: lane l covers row n+(l&15), k-oct (l>>4) of each strip ----
    const float* Bb = B + (long)(n0 + (w << 6) + (lane & 15)) * ldb + ((lane >> 4) << 3);

    f32x4 acc[4];
#pragma unroll
    for (int s = 0; s < 4; ++s) acc[s] = (f32x4){0.f, 0.f, 0.f, 0.f};

    float4 P[4][2], Q[4][2];   // depth-2 prefetch sets (const-indexed only)

    auto LD = [&](float4 (&S)[4][2], int ks) {
#pragma unroll
        for (int s = 0; s < 4; ++s) {
            const float* p = Bb + (long)(s * 16) * ldb + ks * 32;
            S[s][0] = *(const float4*)p;
            S[s][1] = *(const float4*)(p + 4);
        }
    };
    auto STEP = [&](float4 (&S)[4][2], int ks) {
        bfrag af = *(const bfrag*)&Asl[(ks << 9) + (lane << 3)];
#pragma unroll
        for (int s = 0; s < 4; ++s) {
            bfrag bf;
            bf[0] = f2bf(S[s][0].x); bf[1] = f2bf(S[s][0].y);
            bf[2] = f2bf(S[s][0].z); bf[3] = f2bf(S[s][0].w);
            bf[4] = f2bf(S[s][1].x); bf[5] = f2bf(S[s][1].y);
            bf[6] = f2bf(S[s][1].z); bf[7] = f2bf(S[s][1].w);
            acc[s] = __builtin_amdgcn_mfma_f32_16x16x32_bf16(af, bf, acc[s], 0, 0, 0);
        }
    };

    LD(P, 0); LD(Q, 1);
#pragma unroll
    for (int ks = 0; ks < 24; ks += 2) {
        STEP(P, ks);
        if (ks + 2 < 24) LD(P, ks + 2);    // next use 1 full iteration away
        STEP(Q, ks + 1);
        if (ks + 3 < 24) LD(Q, ks + 3);
    }

    // ---- epilogue: D layout col=lane&15, row=(lane>>4)*4+r (m89-verified) ----
    const int gq = lane >> 4;
    const int cn = lane & 15;
#pragma unroll
    for (int s = 0; s < 4; ++s) {
        int n = n0 + (w << 6) + (s << 4) + cn;
        float bv = g.bias ? g.bias[n] : 0.f;
#pragma unroll
        for (int r = 0; r < 4; ++r) {
            int m = m0 + (gq << 2) + r;
            g.C[(long)m * g.ldc + n] = acc[s][r] + bv;
        }
    }
}

// ---------------------------------------------------------------------------
// Fused attention row-0 + FC + 2x LN + score (unchanged -- next target).
// ---------------------------------------------------------------------------
struct ScoreDesc {
    const float *tok_q, *tok_k, *k_task, *U_tok, *U_task, *tokens;
    const float *fcb, *lng, *lnb, *slng, *slnb, *sw, *sbias;
    int T, outOff, blockBase, pad;
};
struct ScoreBatch { ScoreDesc d[2]; };

__device__ inline void block_reduce2(float& a, float& b, float* redA, float* redB, int tid)
{
    int lane = tid & 63, wave = tid >> 6;
#pragma unroll
    for (int off = 32; off; off >>= 1) {
        a += __shfl_down(a, off);
        b += __shfl_down(b, off);
    }
    if (lane == 0) { redA[wave] = a; redB[wave] = b; }
    __syncthreads();
    a = redA[0] + redA[1] + redA[2] + redA[3];
    b = redB[0] + redB[1] + redB[2] + redB[3];
    __syncthreads();
}

__global__ __launch_bounds__(256) void score_kernel(ScoreBatch batch, float* __restrict__ out)
{
    const int si = (blockIdx.x >= batch.d[1].blockBase) ? 1 : 0;
    const ScoreDesc g = batch.d[si];
    const int bid = blockIdx.x - g.blockBase;
    const int T = g.T;
    const int b = bid / T;
    const int t = bid - b * T;
    const int tid = threadIdx.x;
    const int lane = tid & 63;
    const int wave = tid >> 6;   // == head

    __shared__ float coef[HEADS][2];
    __shared__ float redA[4], redB[4];

    {
        const float4* q4  = (const float4*)(g.tok_q  + (long)t * HDIM + wave * DIM);
        const float4* kt4 = (const float4*)(g.tok_k  + (long)t * HDIM + wave * DIM);
        const float4* kb4 = (const float4*)(g.k_task + (long)b * HDIM + wave * DIM);
        float s00 = 0.f, s01 = 0.f;
#pragma unroll
        for (int j = 0; j < 3; ++j) {
            int idx = lane + 64 * j;
            float4 qv = q4[idx], kt = kt4[idx], kb = kb4[idx];
            s00 += qv.x * kt.x + qv.y * kt.y + qv.z * kt.z + qv.w * kt.w;
            s01 += qv.x * kb.x + qv.y * kb.y + qv.z * kb.z + qv.w * kb.w;
        }
#pragma unroll
        for (int off = 32; off; off >>= 1) {
            s00 += __shfl_down(s00, off);
            s01 += __shfl_down(s01, off);
        }
        if (lane == 0) {
            const float scale = 0.03608439182435161f;  // 1/sqrt(768)
            float x0 = s00 * scale, x1 = s01 * scale;
            float mx = fmaxf(x0, x1);
            float e0 = expf(x0 - mx), e1 = expf(x1 - mx);
            float inv = 1.f / (e0 + e1);
            coef[wave][0] = e0 * inv;
            coef[wave][1] = e1 * inv;
        }
    }
    __syncthreads();

    const float c00 = coef[0][0], c01 = coef[0][1];
    const float c10 = coef[1][0], c11 = coef[1][1];
    const float c20 = coef[2][0], c21 = coef[2][1];
    const float c30 = coef[3][0], c31 = coef[3][1];

    float r[3];
    float sum = 0.f, sq = 0.f;
    const float* Ut = g.U_tok  + (long)t * HDIM;
    const float* Ub = g.U_task + (long)b * HDIM;
#pragma unroll
    for (int j = 0; j < 3; ++j) {
        int d = tid + j * 256;
        float v = g.fcb[d] + g.tokens[(long)t * DIM + d];
        v += c00 * Ut[d]           + c01 * Ub[d];
        v += c10 * Ut[DIM + d]     + c11 * Ub[DIM + d];
        v += c20 * Ut[2 * DIM + d] + c21 * Ub[2 * DIM + d];
        v += c30 * Ut[3 * DIM + d] + c31 * Ub[3 * DIM + d];
        r[j] = v;
        sum += v;
        sq += v * v;
    }
    block_reduce2(sum, sq, redA, redB, tid);
    float mean = sum * (1.f / DIM);
    float var = sq * (1.f / DIM) - mean * mean;
    float inv = rsqrtf(var + 1e-5f);

    float y[3];
    float sum2 = 0.f, sq2 = 0.f;
#pragma unroll
    for (int j = 0; j < 3; ++j) {
        int d = tid + j * 256;
        float v = (r[j] - mean) * inv * g.lng[d] + g.lnb[d];
        y[j] = v;
        sum2 += v;
        sq2 += v * v;
    }
    block_reduce2(sum2, sq2, redA, redB, tid);
    float mean2 = sum2 * (1.f / DIM);
    float var2 = sq2 * (1.f / DIM) - mean2 * mean2;
    float inv2 = rsqrtf(var2 + 1e-5f);

    float partial = 0.f, dummy = 0.f;
#pragma unroll
    for (int j = 0; j < 3; ++j) {
        int d = tid + j * 256;
        float c = (y[j] - mean2) * inv2 * g.slng[d] + g.slnb[d];
        partial += c * g.sw[d];
    }
    block_reduce2(partial, dummy, redA, redB, tid);
    if (tid == 0) out[(long)b * 80 + g.outOff + t] = partial + g.sbias[0];
}

// ---------------------------------------------------------------------------
extern "C" void kernel_launch(void* const* d_in, const int* in_sizes, int n_in,
                              void* d_out, int out_size, void* d_ws, size_t ws_size,
                              hipStream_t stream)
{
    const float* task_emb    = (const float*)d_in[0];
    const float* tokens_l1   = (const float*)d_in[1];
    const float* tokens_l2   = (const float*)d_in[2];
    const float* task_proj_w = (const float*)d_in[3];
    const float* task_proj_b = (const float*)d_in[4];

    const float* wq1  = (const float*)d_in[5];
    const float* wk1  = (const float*)d_in[6];
    const float* wv1  = (const float*)d_in[7];
    const float* fcw1 = (const float*)d_in[8];
    const float* fcb1 = (const float*)d_in[9];
    const float* lng1 = (const float*)d_in[10];
    const float* lnb1 = (const float*)d_in[11];
    const float* slng1= (const float*)d_in[12];
    const float* slnb1= (const float*)d_in[13];
    const float* sw1  = (const float*)d_in[14];
    const float* sb1  = (const float*)d_in[15];

    const float* wq2  = (const float*)d_in[16];
    const float* wk2  = (const float*)d_in[17];
    const float* wv2  = (const float*)d_in[18];
    const float* fcw2 = (const float*)d_in[19];
    const float* fcb2 = (const float*)d_in[20];
    const float* lng2 = (const float*)d_in[21];
    const float* lnb2 = (const float*)d_in[22];
    const float* slng2= (const float*)d_in[23];
    const float* slnb2= (const float*)d_in[24];
    const float* sw2  = (const float*)d_in[25];
    const float* sb2  = (const float*)d_in[26];

    float* out = (float*)d_out;

    float* ws = (float*)d_ws;
    float* task_p   = ws;
    float* tq1      = task_p   +  98304;
    float* tk1      = tq1      +  49152;
    float* tv1      = tk1      +  49152;
    float* ut1      = tv1      +  49152;
    float* tq2      = ut1      +  49152;
    float* tk2      = tq2      + 196608;
    float* tv2      = tk2      + 196608;
    float* ut2      = tv2      + 196608;
    float* ktask1   = ut2      + 196608;
    float* vtask1   = ktask1   + 393216;
    float* utask1   = vtask1   + 393216;
    float* ktask2   = utask1   + 393216;
    float* vtask2   = ktask2   + 393216;
    float* utask2   = vtask2   + 393216;

    auto mkDesc = [](const float* A, int lda, const float* B, int ldb,
                     const float* bias, float* C, int ldc,
                     int M, int N, int K, int base) {
        GemmDesc g;
        g.A = A; g.B = B; g.bias = bias; g.C = C;
        g.lda = lda; g.ldb = ldb; g.ldc = ldc;
        g.M = M; g.N = N; g.K = K;
        g.blockBase = base; g.nTiles = N / 256;
        return g;
    };
    auto blocksOf = [](int M, int N) { return (M / 16) * (N / 256); };

    // ---- stage A: task_p + token q/k/v projections (7 descs, 204 blocks) ----
    {
        GemmBatch ba; int base = 0, nd = 0;
        ba.d[nd++] = mkDesc(task_emb, DIM, task_proj_w, DIM, task_proj_b,
                            task_p, DIM, BATCH, DIM, DIM, base);
        base += blocksOf(BATCH, DIM);
        const float* tA[2] = { tokens_l1, tokens_l2 };
        int tT[2] = { 16, 64 };
        const float* tW[2][3] = { { wq1, wk1, wv1 }, { wq2, wk2, wv2 } };
        float* tC[2][3] = { { tq1, tk1, tv1 }, { tq2, tk2, tv2 } };
        for (int l = 0; l < 2; ++l)
            for (int w = 0; w < 3; ++w) {
                ba.d[nd++] = mkDesc(tA[l], DIM, tW[l][w], DIM, nullptr,
                                    tC[l][w], HDIM, tT[l], HDIM, DIM, base);
                base += blocksOf(tT[l], HDIM);
            }
        ba.nDesc = nd;
        gemm_bf16<<<dim3(base), dim3(256), 0, stream>>>(ba);
    }

    // ---- stage B: k_task/v_task + U_tok per head (12 descs, 444 blocks) ----
    {
        GemmBatch bb; int base = 0, nd = 0;
        const float* kw[2] = { wk1, wk2 };
        const float* vw[2] = { wv1, wv2 };
        float* kc[2] = { ktask1, ktask2 };
        float* vc[2] = { vtask1, vtask2 };
        for (int l = 0; l < 2; ++l) {
            bb.d[nd++] = mkDesc(task_p, DIM, kw[l], DIM, nullptr,
                                kc[l], HDIM, BATCH, HDIM, DIM, base);
            base += blocksOf(BATCH, HDIM);
            bb.d[nd++] = mkDesc(task_p, DIM, vw[l], DIM, nullptr,
                                vc[l], HDIM, BATCH, HDIM, DIM, base);
            base += blocksOf(BATCH, HDIM);
        }
        const float* fw[2] = { fcw1, fcw2 };
        float* tv[2] = { tv1, tv2 };
        float* ut[2] = { ut1, ut2 };
        int tT[2] = { 16, 64 };
        for (int l = 0; l < 2; ++l)
            for (int h = 0; h < HEADS; ++h) {
                bb.d[nd++] = mkDesc(tv[l] + h * DIM, HDIM, fw[l] + h * DIM, HDIM,
                                    nullptr, ut[l] + h * DIM, HDIM,
                                    tT[l], DIM, DIM, base);
                base += blocksOf(tT[l], DIM);
            }
        bb.nDesc = nd;
        gemm_bf16<<<dim3(base), dim3(256), 0, stream>>>(bb);
    }

    // ---- stage C: U_task per head per level (8 descs, 192 blocks) ----
    {
        GemmBatch bc; int base = 0, nd = 0;
        const float* fw[2] = { fcw1, fcw2 };
        float* vt[2] = { vtask1, vtask2 };
        float* utk[2] = { utask1, utask2 };
        for (int l = 0; l < 2; ++l)
            for (int h = 0; h < HEADS; ++h) {
                bc.d[nd++] = mkDesc(vt[l] + h * DIM, HDIM, fw[l] + h * DIM, HDIM,
                                    nullptr, utk[l] + h * DIM, HDIM,
                                    BATCH, DIM, DIM, base);
                base += blocksOf(BATCH, DIM);
            }
        bc.nDesc = nd;
        gemm_bf16<<<dim3(base), dim3(256), 0, stream>>>(bc);
    }

    // ---- stage D: both score levels, one dispatch ----
    {
        ScoreBatch sb;
        sb.d[0].tok_q = tq1; sb.d[0].tok_k = tk1; sb.d[0].k_task = ktask1;
        sb.d[0].U_tok = ut1; sb.d[0].U_task = utask1; sb.d[0].tokens = tokens_l1;
        sb.d[0].fcb = fcb1; sb.d[0].lng = lng1; sb.d[0].lnb = lnb1;
        sb.d[0].slng = slng1; sb.d[0].slnb = slnb1; sb.d[0].sw = sw1; sb.d[0].sbias = sb1;
        sb.d[0].T = 16; sb.d[0].outOff = 0; sb.d[0].blockBase = 0; sb.d[0].pad = 0;
        sb.d[1].tok_q = tq2; sb.d[1].tok_k = tk2; sb.d[1].k_task = ktask2;
        sb.d[1].U_tok = ut2; sb.d[1].U_task = utask2; sb.d[1].tokens = tokens_l2;
        sb.d[1].fcb = fcb2; sb.d[1].lng = lng2; sb.d[1].lnb = lnb2;
        sb.d[1].slng = slng2; sb.d[1].slnb = slnb2; sb.d[1].sw = sw2; sb.d[1].sbias = sb2;
        sb.d[1].T = 64; sb.d[1].outOff = 16; sb.d[1].blockBase = BATCH * 16; sb.d[1].pad = 0;
        score_kernel<<<dim3(BATCH * 16 + BATCH * 64), dim3(256), 0, stream>>>(sb, out);
    }
}